// Round 3
// baseline (1306.253 us; speedup 1.0000x reference)
//
#include <hip/hip_runtime.h>
#include <hip/hip_bf16.h>

#define BB 4
#define SS 1024
#define HID 1024
#define NH 16
#define NKV 4
#define DH 64
#define NREP 4

typedef __hip_bfloat16 bf16;

__device__ inline float toF(float x) { return x; }
__device__ inline float toF(bf16 x) { return __bfloat162float(x); }

// ---------------------------------------------------------------------------
// Tiled vector GEMM: C[M,N] = A[M,K] @ Bw[K,N], fp32 accumulate.
// A: fp32 or bf16 row-major; Bw: fp32 row-major; C: bf16 or fp32.
// BM=BN=64, BK=16, 256 threads, 4x4 outputs per thread. M,N multiples of 64.
// ---------------------------------------------------------------------------
template <typename AT, bool OUT_BF16>
__global__ __launch_bounds__(256) void gemm_tiled(const AT* __restrict__ A,
                                                  const float* __restrict__ Bw,
                                                  void* __restrict__ Cv,
                                                  int M, int N, int K) {
  __shared__ float As[64][17];
  __shared__ float Bs[16][64];
  const int t = threadIdx.x;
  const int tx = t & 15;
  const int ty = t >> 4;
  const int rowBase = blockIdx.y * 64;
  const int colBase = blockIdx.x * 64;

  float acc[4][4] = {};

  for (int k0 = 0; k0 < K; k0 += 16) {
#pragma unroll
    for (int i = 0; i < 4; i++) {
      int idx = t + i * 256;  // 0..1023
      int m = idx >> 4;
      int kk = idx & 15;
      As[m][kk] = toF(A[(size_t)(rowBase + m) * K + k0 + kk]);
    }
#pragma unroll
    for (int i = 0; i < 4; i++) {
      int idx = t + i * 256;
      int kk = idx >> 6;
      int n = idx & 63;
      Bs[kk][n] = Bw[(size_t)(k0 + kk) * N + colBase + n];
    }
    __syncthreads();

#pragma unroll
    for (int kk = 0; kk < 16; kk++) {
      float a[4], b[4];
#pragma unroll
      for (int i = 0; i < 4; i++) a[i] = As[ty * 4 + i][kk];
#pragma unroll
      for (int j = 0; j < 4; j++) b[j] = Bs[kk][tx * 4 + j];
#pragma unroll
      for (int i = 0; i < 4; i++)
#pragma unroll
        for (int j = 0; j < 4; j++) acc[i][j] += a[i] * b[j];
    }
    __syncthreads();
  }

#pragma unroll
  for (int i = 0; i < 4; i++) {
#pragma unroll
    for (int j = 0; j < 4; j++) {
      size_t r = rowBase + ty * 4 + i;
      size_t c = colBase + tx * 4 + j;
      if (OUT_BF16)
        ((bf16*)Cv)[r * N + c] = __float2bfloat16(acc[i][j]);
      else
        ((float*)Cv)[r * N + c] = acc[i][j];
    }
  }
}

// ---------------------------------------------------------------------------
// Attention: one block per (q-row, kv-head, batch). Handles the NREP=4 query
// heads sharing that kv head. q/k/v/attn bf16 in ws; bias/mask fp32/int32
// inputs; all math fp32.
// ---------------------------------------------------------------------------
__global__ __launch_bounds__(256) void attn_kernel(
    const bf16* __restrict__ q,      // [B, S, NH*DH]
    const bf16* __restrict__ kmat,   // [B, S, NKV*DH]
    const bf16* __restrict__ vmat,   // [B, S, NKV*DH]
    const float* __restrict__ bias,  // [B, NH, S, S]
    const int* __restrict__ mask,    // [B, 1, S, S]
    bf16* __restrict__ attn)         // [B, S, NH*DH]
{
  const int sq = blockIdx.x;
  const int kvh = blockIdx.y;
  const int b = blockIdx.z;

  __shared__ float qs[NREP][DH];       // 1 KB
  __shared__ float sc[NREP][SS];       // 16 KB
  __shared__ float part[4][NREP][DH];  // 4 KB

  const int t = threadIdx.x;

  // load the 4 query heads' vectors (256 contiguous bf16)
  ((float*)qs)[t] =
      __bfloat162float(q[(size_t)(b * SS + sq) * (NH * DH) + kvh * NREP * DH + t]);
  __syncthreads();

  // ---- phase 1: scores = q.kT/8 + bias, masked ----
  const bf16* kb = kmat + (size_t)b * SS * (NKV * DH) + kvh * DH;
  const int* mrow = mask + ((size_t)b * SS + sq) * SS;
  const float* brow = bias + (((size_t)b * NH + kvh * NREP) * SS + sq) * SS;

#pragma unroll
  for (int i = 0; i < 4; i++) {
    int kk = t + i * 256;
    const bf16* krow = kb + (size_t)kk * (NKV * DH);
    float dd[NREP] = {0.f, 0.f, 0.f, 0.f};
#pragma unroll
    for (int dv = 0; dv < DH; dv++) {
      float kx = __bfloat162float(krow[dv]);
#pragma unroll
      for (int r = 0; r < NREP; r++) dd[r] += qs[r][dv] * kx;
    }
    bool live = mrow[kk] != 0;
#pragma unroll
    for (int r = 0; r < NREP; r++) {
      float val = dd[r] * 0.125f + brow[(size_t)r * SS * SS + kk];
      sc[r][kk] = live ? val : -1e9f;
    }
  }
  __syncthreads();

  // ---- phase 2: softmax, one wave per head-row ----
  {
    const int wave = t >> 6;
    const int lane = t & 63;
    float mx = -1e30f;
    for (int i = lane; i < SS; i += 64) mx = fmaxf(mx, sc[wave][i]);
#pragma unroll
    for (int off = 32; off; off >>= 1) mx = fmaxf(mx, __shfl_xor(mx, off));
    float sum = 0.f;
    for (int i = lane; i < SS; i += 64) {
      float e = __expf(sc[wave][i] - mx);
      sc[wave][i] = e;
      sum += e;
    }
#pragma unroll
    for (int off = 32; off; off >>= 1) sum += __shfl_xor(sum, off);
    float inv = 1.0f / sum;
    for (int i = lane; i < SS; i += 64) sc[wave][i] *= inv;
  }
  __syncthreads();

  // ---- phase 3: out = w @ V, chunked over keys then LDS-reduced ----
  {
    const int d = t & 63;
    const int c = t >> 6;
    const bf16* vb = vmat + (size_t)b * SS * (NKV * DH) + kvh * DH + d;
    float o[NREP] = {0.f, 0.f, 0.f, 0.f};
    for (int kk = c * 256; kk < c * 256 + 256; kk++) {
      float vv = __bfloat162float(vb[(size_t)kk * (NKV * DH)]);
#pragma unroll
      for (int r = 0; r < NREP; r++) o[r] += sc[r][kk] * vv;
    }
#pragma unroll
    for (int r = 0; r < NREP; r++) part[c][r][d] = o[r];
    __syncthreads();
    if (c == 0) {
#pragma unroll
      for (int r = 0; r < NREP; r++) {
        float s = part[0][r][d] + part[1][r][d] + part[2][r][d] + part[3][r][d];
        attn[(size_t)(b * SS + sq) * (NH * DH) + (kvh * NREP + r) * DH + d] =
            __float2bfloat16(s);
      }
    }
  }
}

// ---------------------------------------------------------------------------
extern "C" void kernel_launch(void* const* d_in, const int* in_sizes, int n_in,
                              void* d_out, int out_size, void* d_ws,
                              size_t ws_size, hipStream_t stream) {
  const float* hs = (const float*)d_in[0];    // [B,S,HID]      fp32
  const float* bias = (const float*)d_in[1];  // [B,NH,S,S]     fp32
  const int* mask = (const int*)d_in[2];      // [B,1,S,S]      int32
  const float* Wq = (const float*)d_in[3];    // [HID, NH*DH]   fp32
  const float* Wk = (const float*)d_in[4];    // [HID, NKV*DH]  fp32
  const float* Wv = (const float*)d_in[5];    // [HID, NKV*DH]  fp32
  const float* Wo = (const float*)d_in[6];    // [HID, HID]     fp32
  float* out = (float*)d_out;                 // [B,S,HID]      fp32

  bf16* q = (bf16*)d_ws;                      // [B,S,NH*DH]   8 MB
  bf16* k = q + (size_t)BB * SS * NH * DH;    // [B,S,NKV*DH]  2 MB
  bf16* v = k + (size_t)BB * SS * NKV * DH;   // [B,S,NKV*DH]  2 MB
  bf16* at = v + (size_t)BB * SS * NKV * DH;  // [B,S,NH*DH]   8 MB

  const int M = BB * SS;  // 4096

  gemm_tiled<float, true>
      <<<dim3(NH * DH / 64, M / 64), 256, 0, stream>>>(hs, Wq, q, M, NH * DH, HID);
  gemm_tiled<float, true>
      <<<dim3(NKV * DH / 64, M / 64), 256, 0, stream>>>(hs, Wk, k, M, NKV * DH, HID);
  gemm_tiled<float, true>
      <<<dim3(NKV * DH / 64, M / 64), 256, 0, stream>>>(hs, Wv, v, M, NKV * DH, HID);

  attn_kernel<<<dim3(SS, NKV, BB), 256, 0, stream>>>(q, k, v, bias, mask, at);

  gemm_tiled<bf16, false>
      <<<dim3(HID / 64, M / 64), 256, 0, stream>>>(at, Wo, out, M, HID, HID);
}